// Round 9
// baseline (2496.182 us; speedup 1.0000x reference)
//
#include <hip/hip_runtime.h>
#include <hip/hip_bf16.h>
#include <math.h>

#define BATCH 32
#define C 256
#define HW 3136
#define OUTROW 32896
#define KSPLIT 7
#define KCHUNK 448   // HW / KSPLIT
#define KC32 98      // HW / 32
#define KCG 49       // kc-pair groups per batch
#define SLAB 16384   // shorts per kc slab (hi 8192 + lo 8192 interleaved)
#define HALF 8192

// Interleaved fragment-major layouts (shorts):
//   X slab s = b*98 + kc :  X[s*SLAB + row*32 + (k&31)]        (hi)
//                           X[s*SLAB + HALF + row*32 + (k&31)] (lo)
//   M slab s = b*8 + kc  :  same, 256x256 matrices, 8 slabs each.

typedef __bf16 b8v __attribute__((ext_vector_type(8)));
typedef float  f4v __attribute__((ext_vector_type(4)));
typedef unsigned short u16x8 __attribute__((ext_vector_type(8)));

__device__ __forceinline__ unsigned short f2bf(float f) {
    union { float f; unsigned u; } v; v.f = f;
    unsigned r = v.u + 0x7FFFu + ((v.u >> 16) & 1u);
    return (unsigned short)(r >> 16);
}
__device__ __forceinline__ float bf2f(unsigned short h) {
    union { unsigned u; float f; } v; v.u = ((unsigned)h) << 16; return v.f;
}
__device__ __forceinline__ void split2(float x, unsigned short& h, unsigned short& l) {
    h = f2bf(x);
    l = f2bf(x - bf2f(h));
}

__device__ __forceinline__ float wave_sum(float v) {
    for (int o = 32; o; o >>= 1) v += __shfl_down(v, o, 64);
    return v;
}

// ---------------------------------------------------------------------------
// prep: x -> hi/lo bf16 split, interleaved fragment-major X layout.
// ---------------------------------------------------------------------------
__global__ __launch_bounds__(256, 2) void k_prep(const float* __restrict__ x,
                                                 unsigned short* __restrict__ X,
                                                 float* __restrict__ psum,
                                                 float* __restrict__ qsum) {
    const int blk = blockIdx.x;                 // b*KCG + g
    const int b = blk / KCG;
    const int g = blk - b * KCG;
    const int kc0 = g * 2;
    const int t = threadIdx.x;
    const int lane4 = t & 3;                    // 4 lanes per row, 16 floats each
    const int rowoff = t >> 2;                  // 0..63
    const int ko = lane4 * 8;

    const float* xb = x + (size_t)b * C * HW + (size_t)kc0 * 32 + ko;
    unsigned short* s0 = X + (size_t)(b * KC32 + kc0) * SLAB + ko;
    unsigned short* s1 = s0 + SLAB;
    float* ps = psum + (size_t)blk * 256;
    float* qs = qsum + (size_t)blk * 256;

    float4 v[4][4];
#pragma unroll
    for (int it = 0; it < 4; ++it) {
        const float* src = xb + (size_t)(it * 64 + rowoff) * HW;
        v[it][0] = *(const float4*)(src);
        v[it][1] = *(const float4*)(src + 4);
        v[it][2] = *(const float4*)(src + 32);
        v[it][3] = *(const float4*)(src + 36);
    }

#pragma unroll
    for (int it = 0; it < 4; ++it) {
        const int row = it * 64 + rowoff;
        float va[8] = { v[it][0].x, v[it][0].y, v[it][0].z, v[it][0].w,
                        v[it][1].x, v[it][1].y, v[it][1].z, v[it][1].w };
        float vb[8] = { v[it][2].x, v[it][2].y, v[it][2].z, v[it][2].w,
                        v[it][3].x, v[it][3].y, v[it][3].z, v[it][3].w };
        unsigned short ha[8], la[8], hb[8], lb[8];
        float s = 0.f, q = 0.f;
#pragma unroll
        for (int j = 0; j < 8; ++j) {
            split2(va[j], ha[j], la[j]);
            split2(vb[j], hb[j], lb[j]);
            s += va[j] + vb[j];
            q = fmaf(va[j], va[j], q);
            q = fmaf(vb[j], vb[j], q);
        }
        *(u16x8*)(s0 + row * 32) = *(u16x8*)ha;
        *(u16x8*)(s0 + HALF + row * 32) = *(u16x8*)la;
        *(u16x8*)(s1 + row * 32) = *(u16x8*)hb;
        *(u16x8*)(s1 + HALF + row * 32) = *(u16x8*)lb;
        s += __shfl_xor(s, 1, 64);
        s += __shfl_xor(s, 2, 64);
        q += __shfl_xor(q, 1, 64);
        q += __shfl_xor(q, 2, 64);
        if (lane4 == 0) { ps[row] = s; qs[row] = q; }
    }
}

// reduce per-kcg partials -> sbuf (row sums) + trace; also zero NS counters
__global__ __launch_bounds__(256) void k_tr(const float* __restrict__ psum,
                                            const float* __restrict__ qsum,
                                            float* __restrict__ sbuf,
                                            float* __restrict__ trbuf,
                                            float* __restrict__ strbuf,
                                            unsigned* __restrict__ cnt) {
    const int b = blockIdx.x, t = threadIdx.x;
    const float* ps = psum + (size_t)b * KCG * 256 + t;
    const float* qs = qsum + (size_t)b * KCG * 256 + t;
    float s = 0.f, q = 0.f;
#pragma unroll 7
    for (int g = 0; g < KCG; ++g) {
        s += ps[(size_t)g * 256];
        q += qs[(size_t)g * 256];
    }
    sbuf[b * C + t] = s;
    const float invn = 1.f / (float)HW, invn2 = invn * invn;
    float v = q * invn - s * s * invn2;
    v = wave_sum(v);
    __shared__ float red[4];
    if ((t & 63) == 0) red[t >> 6] = v;
    __syncthreads();
    if (t == 0) {
        float tr = red[0] + red[1] + red[2] + red[3];
        trbuf[b] = tr;
        strbuf[b] = sqrtf(tr);
        cnt[b] = 0u;   // visible to k_ns via kernel-boundary flush
    }
}

// ---------------------------------------------------------------------------
// gram split-K: 1-wave blocks, 64x64 tile, fragment-major coalesced loads,
// register dbuf, XCD-pinned. Grid 2240 x 64.
// ---------------------------------------------------------------------------
__global__ __launch_bounds__(64, 1) void k_gram_split(
    const unsigned short* __restrict__ X, float* __restrict__ part) {
    const int bid = blockIdx.x;
    const int x8 = bid & 7;
    const int t8 = bid >> 3;
    const int pairIdx = t8 % 10;
    const int g = (t8 / 10) * 8 + x8;   // 0..223, pinned to XCD x8
    const int b = g & 31;
    const int z = g >> 5;               // 0..6

    int p = pairIdx, tm = 0, rem = 4;
    while (p >= rem) { p -= rem; ++tm; --rem; }
    const int tn = tm + p;

    const int lane = threadIdx.x & 63;
    const int q = lane >> 4, r = lane & 15;
    const int kc0 = z * (KCHUNK / 32);
    const size_t matb = (size_t)b * KC32 * SLAB;

    int oA[4], oB[4];
#pragma unroll
    for (int i = 0; i < 4; ++i) {
        oA[i] = (tm * 64 + i * 16 + r) * 32 + q * 8;
        oB[i] = (tn * 64 + i * 16 + r) * 32 + q * 8;
    }

    f4v acc[4][4] = {};
    b8v fAh[2][4], fAl[2][4], fBh[2][4], fBl[2][4];
#define LDG(buf, kc)                                                     \
    do {                                                                 \
        const size_t sb = matb + (size_t)(kc0 + (kc)) * SLAB;            \
        for (int i = 0; i < 4; ++i) {                                    \
            fAh[buf][i] = *(const b8v*)(X + sb + oA[i]);                 \
            fAl[buf][i] = *(const b8v*)(X + sb + HALF + oA[i]);          \
            fBh[buf][i] = *(const b8v*)(X + sb + oB[i]);                 \
            fBl[buf][i] = *(const b8v*)(X + sb + HALF + oB[i]);          \
        }                                                                \
    } while (0)

    LDG(0, 0);
#pragma unroll
    for (int kc = 0; kc < KCHUNK / 32; ++kc) {
        const int cb = kc & 1, nb = cb ^ 1;
        if (kc < KCHUNK / 32 - 1) LDG(nb, kc + 1);
#pragma unroll
        for (int i = 0; i < 4; ++i)
#pragma unroll
            for (int j = 0; j < 4; ++j) {
                acc[i][j] = __builtin_amdgcn_mfma_f32_16x16x32_bf16(fAh[cb][i], fBh[cb][j], acc[i][j], 0, 0, 0);
                acc[i][j] = __builtin_amdgcn_mfma_f32_16x16x32_bf16(fAh[cb][i], fBl[cb][j], acc[i][j], 0, 0, 0);
                acc[i][j] = __builtin_amdgcn_mfma_f32_16x16x32_bf16(fAl[cb][i], fBh[cb][j], acc[i][j], 0, 0, 0);
            }
    }
#undef LDG

    float* pt = part + (((size_t)pairIdx * BATCH + b) * KSPLIT + z) * 4096;
#pragma unroll
    for (int i = 0; i < 4; ++i)
#pragma unroll
        for (int j = 0; j < 4; ++j)
#pragma unroll
            for (int reg = 0; reg < 4; ++reg) {
                int row = i * 16 + q * 4 + reg;
                int col = j * 16 + r;
                pt[row * 64 + col] = acc[i][j][reg];
            }
}

// ---------------------------------------------------------------------------
// reduce partials -> a and z0 (interleaved fragment-major), mirrored via LDS
// ---------------------------------------------------------------------------
__global__ __launch_bounds__(256) void k_reduce(
    const float* __restrict__ part, const float* __restrict__ sbuf,
    const float* __restrict__ trbuf,
    unsigned short* __restrict__ A, unsigned short* __restrict__ Z) {
    const int b = blockIdx.y;
    int p = blockIdx.x, tm = 0, rem = 4;
    while (p >= rem) { p -= rem; ++tm; --rem; }
    const int tn = tm + p;

    const float* pb = part + ((size_t)blockIdx.x * BATCH + b) * KSPLIT * 4096;
    const int t = threadIdx.x;
    const int row = t >> 2, c0 = (t & 3) * 16;

    float s[16];
#pragma unroll
    for (int u = 0; u < 16; ++u) s[u] = 0.f;
    for (int sp = 0; sp < KSPLIT; ++sp) {
        const float* q4 = pb + sp * 4096 + row * 64 + c0;
#pragma unroll
        for (int u4 = 0; u4 < 4; ++u4) {
            float4 v = *(const float4*)(q4 + u4 * 4);
            s[u4 * 4 + 0] += v.x; s[u4 * 4 + 1] += v.y;
            s[u4 * 4 + 2] += v.z; s[u4 * 4 + 3] += v.w;
        }
    }

    const float invn = 1.f / (float)HW, invn2 = invn * invn;
    const float tr = trbuf[b];
    const int gi = tm * 64 + row;
    const float si = sbuf[b * C + gi];
    const size_t mb = (size_t)b * 8 * SLAB;

    __shared__ unsigned short tAh[64][66], tAl[64][66], tZh[64][66], tZl[64][66];
    unsigned short vAh[16], vAl[16], vZh[16], vZl[16];
#pragma unroll
    for (int u = 0; u < 16; ++u) {
        int gj = tn * 64 + c0 + u;
        float sj = sbuf[b * C + gj];
        float a = (s[u] * invn - si * sj * invn2) / tr;
        split2(a, vAh[u], vAl[u]);
        float zv = ((gi == gj) ? 1.5f : 0.f) - 0.5f * a;
        split2(zv, vZh[u], vZl[u]);
        tAh[row][c0 + u] = vAh[u]; tAl[row][c0 + u] = vAl[u];
        tZh[row][c0 + u] = vZh[u]; tZl[row][c0 + u] = vZl[u];
    }
#pragma unroll
    for (int u4 = 0; u4 < 4; ++u4) {
        const int col0 = tn * 64 + c0 + u4 * 4;
        const size_t off = mb + (size_t)(col0 >> 5) * SLAB + (size_t)gi * 32 + (col0 & 31);
        *(ushort4*)&A[off] = *(ushort4*)&vAh[u4 * 4];
        *(ushort4*)&A[off + HALF] = *(ushort4*)&vAl[u4 * 4];
        *(ushort4*)&Z[off] = *(ushort4*)&vZh[u4 * 4];
        *(ushort4*)&Z[off + HALF] = *(ushort4*)&vZl[u4 * 4];
    }
    if (tm != tn) {
        __syncthreads();
        const int mr = t >> 2, mc0 = (t & 3) * 16;
        const int gim = tn * 64 + mr;
        unsigned short wAh[16], wAl[16], wZh[16], wZl[16];
#pragma unroll
        for (int u = 0; u < 16; ++u) {
            wAh[u] = tAh[mc0 + u][mr]; wAl[u] = tAl[mc0 + u][mr];
            wZh[u] = tZh[mc0 + u][mr]; wZl[u] = tZl[mc0 + u][mr];
        }
#pragma unroll
        for (int u4 = 0; u4 < 4; ++u4) {
            const int col0 = tm * 64 + mc0 + u4 * 4;
            const size_t off = mb + (size_t)(col0 >> 5) * SLAB + (size_t)gim * 32 + (col0 & 31);
            *(ushort4*)&A[off] = *(ushort4*)&wAh[u4 * 4];
            *(ushort4*)&A[off + HALF] = *(ushort4*)&wAl[u4 * 4];
            *(ushort4*)&Z[off] = *(ushort4*)&wZh[u4 * 4];
            *(ushort4*)&Z[off + HALF] = *(ushort4*)&wZl[u4 * 4];
        }
    }
}

// ---------------------------------------------------------------------------
// NS core: one wave, 32x32 tile, K=256, interleaved fragment-major loads.
// ---------------------------------------------------------------------------
__device__ __forceinline__ void wave_gemm32(
    const unsigned short* __restrict__ A, const unsigned short* __restrict__ B,
    int rowA, int rowB, f4v acc[2][2]) {
    const int lane = threadIdx.x & 63;
    const int q = lane >> 4, r = lane & 15;
    int oA[2], oB[2];
#pragma unroll
    for (int i = 0; i < 2; ++i) {
        oA[i] = (rowA + i * 16 + r) * 32 + q * 8;
        oB[i] = (rowB + i * 16 + r) * 32 + q * 8;
    }
    b8v fAh[2][2], fAl[2][2], fBh[2][2], fBl[2][2];
#define LD(buf, kc)                                              \
    do {                                                         \
        const size_t sb = (size_t)(kc) * SLAB;                   \
        for (int i = 0; i < 2; ++i) {                            \
            fAh[buf][i] = *(const b8v*)(A + sb + oA[i]);         \
            fAl[buf][i] = *(const b8v*)(A + sb + HALF + oA[i]);  \
            fBh[buf][i] = *(const b8v*)(B + sb + oB[i]);         \
            fBl[buf][i] = *(const b8v*)(B + sb + HALF + oB[i]);  \
        }                                                        \
    } while (0)

    LD(0, 0);
#pragma unroll
    for (int kc = 0; kc < 8; ++kc) {
        const int cb = kc & 1, nb = cb ^ 1;
        if (kc < 7) LD(nb, kc + 1);
#pragma unroll
        for (int i = 0; i < 2; ++i)
#pragma unroll
            for (int j = 0; j < 2; ++j) {
                acc[i][j] = __builtin_amdgcn_mfma_f32_16x16x32_bf16(fAh[cb][i], fBh[cb][j], acc[i][j], 0, 0, 0);
                acc[i][j] = __builtin_amdgcn_mfma_f32_16x16x32_bf16(fAh[cb][i], fBl[cb][j], acc[i][j], 0, 0, 0);
                acc[i][j] = __builtin_amdgcn_mfma_f32_16x16x32_bf16(fAl[cb][i], fBh[cb][j], acc[i][j], 0, 0, 0);
            }
    }
#undef LD
}

// store one 32x32 result tile into interleaved fragment-major D (direct)
__device__ __forceinline__ void store_tile32(
    unsigned short* __restrict__ D, int tm, int tn, const f4v acc[2][2], bool modeT) {
    const int lane = threadIdx.x & 63, q = lane >> 4, r = lane & 15;
#pragma unroll
    for (int i = 0; i < 2; ++i)
#pragma unroll
        for (int j = 0; j < 2; ++j) {
            const int gj = tn * 32 + j * 16 + r;
            const size_t cbase = (size_t)(gj >> 5) * SLAB + (gj & 31);
#pragma unroll
            for (int reg = 0; reg < 4; ++reg) {
                const int gi = tm * 32 + i * 16 + q * 4 + reg;
                float v = acc[i][j][reg];
                if (modeT) v = ((gi == gj) ? 1.5f : 0.f) - 0.5f * v;
                unsigned short h, l;
                split2(v, h, l);
                D[cbase + (size_t)gi * 32] = h;
                D[cbase + HALF + (size_t)gi * 32] = l;
            }
        }
}

// ---------------------------------------------------------------------------
// Fused NS chain: cooperative launch (co-residency guaranteed), but NO
// grid.sync — per-batch barriers only (64 blocks/batch, XCD-local via bid&7
// pinning). 2048 blocks x 64 threads = 8 blocks/CU.
// ---------------------------------------------------------------------------
__global__ __launch_bounds__(64, 2) void k_ns(
    unsigned short* __restrict__ PA, unsigned short* __restrict__ PB,
    unsigned short* __restrict__ PC, unsigned short* __restrict__ PD,
    unsigned short* __restrict__ PE, float* __restrict__ outF,
    const float* __restrict__ strbuf, unsigned* __restrict__ cnt) {
    const int bid = blockIdx.x;
    const int x8 = bid & 7;
    const int w = bid >> 3;                // 0..255
    const int b = x8 + 8 * (w >> 6);       // 0..31, pinned to XCD x8
    const int tile = w & 63;
    const int tm = tile >> 3, tn = tile & 7;
    const size_t mo = (size_t)b * 8 * SLAB;
    unsigned* cb = cnt + b;

#pragma unroll 1
    for (int s = 0; s < 8; ++s) {
        const unsigned short *A, *B, *A2 = nullptr, *B2 = nullptr;
        unsigned short *D, *D2 = nullptr;
        bool modeT = false;
        switch (s) {
            case 0: A = PA; B = PB; D = PC; break;                              // Y0
            case 1: A = PB; B = PC; D = PD; modeT = true; break;                // T0
            case 2: A = PC; B = PD; D = PA; A2 = PD; B2 = PB; D2 = PE; break;   // Y1,Z1
            case 3: A = PE; B = PA; D = PB; modeT = true; break;                // T1
            case 4: A = PA; B = PB; D = PC; A2 = PB; B2 = PE; D2 = PD; break;   // Y2,Z2
            case 5: A = PD; B = PC; D = PA; modeT = true; break;                // T2
            case 6: A = PC; B = PA; D = PB; A2 = PA; B2 = PD; D2 = PE; break;   // Y3,Z3
            default: A = PE; B = PB; D = PC; modeT = true; break;               // T3
        }
        {
            f4v acc[2][2] = {};
            wave_gemm32(A + mo, B + mo, tm * 32, tn * 32, acc);
            store_tile32(D + mo, tm, tn, acc, modeT);
        }
        if (A2) {
            f4v acc2[2][2] = {};
            wave_gemm32(A2 + mo, B2 + mo, tm * 32, tn * 32, acc2);
            store_tile32(D2 + mo, tm, tn, acc2, false);
        }
        // per-batch barrier
        __threadfence();
        if (threadIdx.x == 0) {
            __hip_atomic_fetch_add(cb, 1u, __ATOMIC_RELEASE, __HIP_MEMORY_SCOPE_AGENT);
            const unsigned target = 64u * (unsigned)(s + 1);
            while (__hip_atomic_load(cb, __ATOMIC_RELAXED, __HIP_MEMORY_SCOPE_AGENT) < target)
                __builtin_amdgcn_s_sleep(2);
        }
        __syncthreads();
        __threadfence();
    }

    // final: out = triuvec((PB@PC) * sqrt(tr)) — 36 triangular tiles/batch
    if (tile < 36) {
        int p = tile, ttm = 0, rem = 8;
        while (p >= rem) { p -= rem; ++ttm; --rem; }
        const int ttn = ttm + p;
        f4v acc[2][2] = {};
        wave_gemm32(PB + mo, PC + mo, ttm * 32, ttn * 32, acc);
        const int lane = threadIdx.x & 63, q = lane >> 4, r = lane & 15;
        const float sc = strbuf[b];
#pragma unroll
        for (int i = 0; i < 2; ++i)
#pragma unroll
            for (int j = 0; j < 2; ++j) {
                const int gj = ttn * 32 + j * 16 + r;
#pragma unroll
                for (int reg = 0; reg < 4; ++reg) {
                    const int gi = ttm * 32 + i * 16 + q * 4 + reg;
                    if (gj >= gi)
                        outF[(size_t)b * OUTROW + (size_t)(gi * C - (gi * (gi - 1)) / 2) +
                             (gj - gi)] = acc[i][j][reg] * sc;
                }
            }
    }
}

// ---------------------------------------------------------------------------
extern "C" void kernel_launch(void* const* d_in, const int* in_sizes, int n_in,
                              void* d_out, int out_size, void* d_ws, size_t ws_size,
                              hipStream_t stream) {
    const float* x = (const float*)d_in[0];
    float* out = (float*)d_out;

    unsigned short* W = (unsigned short*)d_ws;
    const size_t XS = (size_t)BATCH * KC32 * SLAB;   // interleaved X shorts
    const size_t MS = (size_t)BATCH * 8 * SLAB;      // one interleaved matrix set
    unsigned short* X = W;
    float* sbuf = (float*)(X + XS);
    float* trbuf = sbuf + BATCH * C;
    float* strbuf = trbuf + BATCH;
    unsigned* cnt = (unsigned*)(strbuf + BATCH);     // 32 per-batch barrier counters
    unsigned short* P = (unsigned short*)(cnt + BATCH);
    unsigned short* PA = P + 0 * MS;
    unsigned short* PB = P + 1 * MS;
    unsigned short* PC = P + 2 * MS;
    unsigned short* PD = P + 3 * MS;
    unsigned short* PE = P + 4 * MS;
    // fp32 gram partials alias PC.. (dead until Y0 is written)
    float* part = (float*)PC;                         // 10*32*7*4096 floats
    // prep sum partials alias PA (dead until k_reduce writes it)
    float* psum = (float*)PA;                         // 32*49*256 floats
    float* qsum = psum + (size_t)BATCH * KCG * 256;

    k_prep<<<dim3(BATCH * KCG), 256, 0, stream>>>(x, X, psum, qsum);
    k_tr<<<dim3(BATCH), 256, 0, stream>>>(psum, qsum, sbuf, trbuf, strbuf, cnt);
    k_gram_split<<<dim3(10 * BATCH * KSPLIT), 64, 0, stream>>>(X, part);
    k_reduce<<<dim3(10, BATCH), 256, 0, stream>>>(part, sbuf, trbuf, PA, PB);

    void* args[] = { &PA, &PB, &PC, &PD, &PE, &out, &strbuf, &cnt };
    hipLaunchCooperativeKernel((const void*)k_ns, dim3(2048), dim3(64), args, 0, stream);
}

// Round 10
// 362.130 us; speedup vs baseline: 6.8931x; 6.8931x over previous
//
#include <hip/hip_runtime.h>
#include <hip/hip_bf16.h>
#include <math.h>

#define BATCH 32
#define C 256
#define HW 3136
#define OUTROW 32896
#define KSPLIT 7
#define KCHUNK 448   // HW / KSPLIT
#define KC32 98      // HW / 32
#define G7 14        // groups of 7 kc per batch
#define SLAB 16384   // shorts per kc slab (hi 8192 + lo 8192 interleaved)
#define HALF 8192

// Interleaved fragment-major layouts (shorts):
//   X slab s = b*98 + kc :  X[s*SLAB + row*32 + (k&31)]        (hi)
//                           X[s*SLAB + HALF + row*32 + (k&31)] (lo)
//   M slab s = b*8 + kc  :  same, 256x256 matrices, 8 slabs each.

typedef __bf16 b8v __attribute__((ext_vector_type(8)));
typedef float  f4v __attribute__((ext_vector_type(4)));
typedef unsigned short u16x8 __attribute__((ext_vector_type(8)));

__device__ __forceinline__ unsigned short f2bf(float f) {
    union { float f; unsigned u; } v; v.f = f;
    unsigned r = v.u + 0x7FFFu + ((v.u >> 16) & 1u);
    return (unsigned short)(r >> 16);
}
__device__ __forceinline__ float bf2f(unsigned short h) {
    union { unsigned u; float f; } v; v.u = ((unsigned)h) << 16; return v.f;
}
__device__ __forceinline__ void split2(float x, unsigned short& h, unsigned short& l) {
    h = f2bf(x);
    l = f2bf(x - bf2f(h));
}

__device__ __forceinline__ float wave_sum(float v) {
    for (int o = 32; o; o >>= 1) v += __shfl_down(v, o, 64);
    return v;
}

// ---------------------------------------------------------------------------
// prep: x -> hi/lo bf16 split, interleaved fragment-major X layout.
// Block = (b, 7-kc group, row-quarter). Each lane owns one kc and reads its
// own contiguous 128 B (8 x float4); 7 lanes form an 896-B contiguous read
// window per row. Writes are slab-contiguous 64-B segments. Per-(b,kc,row)
// s/q partials out (reduced over 98 kc by k_reduce).
// ---------------------------------------------------------------------------
__global__ __launch_bounds__(256, 2) void k_prep(const float* __restrict__ x,
                                                 unsigned short* __restrict__ X,
                                                 float* __restrict__ psum,
                                                 float* __restrict__ qsum) {
    const int bid = blockIdx.x;
    const int quad = bid & 3;                  // row quarter (64 rows)
    const int bg = bid >> 2;                   // b*G7 + g
    const int b = bg / G7;
    const int g = bg - b * G7;
    const int t = threadIdx.x;
    if (t >= 252) return;
    const int j = t % 7;
    const int rbase = t / 7;                   // 0..35
    const int kc = g * 7 + j;

    const float* xb = x + (size_t)b * C * HW + (size_t)kc * 32;
    unsigned short* sl = X + (size_t)(b * KC32 + kc) * SLAB;
    float* ps = psum + ((size_t)b * KC32 + kc) * 256;
    float* qs = qsum + ((size_t)b * KC32 + kc) * 256;

#pragma unroll
    for (int p = 0; p < 2; ++p) {
        const int row = quad * 64 + p * 36 + rbase;
        if (row < quad * 64 + 64) {
            const float* src = xb + (size_t)row * HW;
            float4 v[8];
#pragma unroll
            for (int u = 0; u < 8; ++u) v[u] = *(const float4*)(src + u * 4);
            unsigned short h[32], l[32];
            float s = 0.f, q = 0.f;
#pragma unroll
            for (int u = 0; u < 8; ++u) {
                float f0 = v[u].x, f1 = v[u].y, f2 = v[u].z, f3 = v[u].w;
                split2(f0, h[u * 4 + 0], l[u * 4 + 0]);
                split2(f1, h[u * 4 + 1], l[u * 4 + 1]);
                split2(f2, h[u * 4 + 2], l[u * 4 + 2]);
                split2(f3, h[u * 4 + 3], l[u * 4 + 3]);
                s += f0 + f1 + f2 + f3;
                q = fmaf(f0, f0, q); q = fmaf(f1, f1, q);
                q = fmaf(f2, f2, q); q = fmaf(f3, f3, q);
            }
#pragma unroll
            for (int u = 0; u < 4; ++u) {
                *(u16x8*)(sl + (size_t)row * 32 + u * 8) = *(u16x8*)&h[u * 8];
                *(u16x8*)(sl + HALF + (size_t)row * 32 + u * 8) = *(u16x8*)&l[u * 8];
            }
            ps[row] = s;
            qs[row] = q;
        }
    }
}

// ---------------------------------------------------------------------------
// gram split-K: 1-wave blocks, 64x64 tile, fragment-major coalesced loads,
// register dbuf, XCD-pinned. Grid 2240 x 64.
// ---------------------------------------------------------------------------
__global__ __launch_bounds__(64, 1) void k_gram_split(
    const unsigned short* __restrict__ X, float* __restrict__ part) {
    const int bid = blockIdx.x;
    const int x8 = bid & 7;
    const int t8 = bid >> 3;
    const int pairIdx = t8 % 10;
    const int g = (t8 / 10) * 8 + x8;   // 0..223, pinned to XCD x8
    const int b = g & 31;
    const int z = g >> 5;               // 0..6

    int p = pairIdx, tm = 0, rem = 4;
    while (p >= rem) { p -= rem; ++tm; --rem; }
    const int tn = tm + p;

    const int lane = threadIdx.x & 63;
    const int q = lane >> 4, r = lane & 15;
    const int kc0 = z * (KCHUNK / 32);
    const size_t matb = (size_t)b * KC32 * SLAB;

    int oA[4], oB[4];
#pragma unroll
    for (int i = 0; i < 4; ++i) {
        oA[i] = (tm * 64 + i * 16 + r) * 32 + q * 8;
        oB[i] = (tn * 64 + i * 16 + r) * 32 + q * 8;
    }

    f4v acc[4][4] = {};
    b8v fAh[2][4], fAl[2][4], fBh[2][4], fBl[2][4];
#define LDG(buf, kc)                                                     \
    do {                                                                 \
        const size_t sb = matb + (size_t)(kc0 + (kc)) * SLAB;            \
        for (int i = 0; i < 4; ++i) {                                    \
            fAh[buf][i] = *(const b8v*)(X + sb + oA[i]);                 \
            fAl[buf][i] = *(const b8v*)(X + sb + HALF + oA[i]);          \
            fBh[buf][i] = *(const b8v*)(X + sb + oB[i]);                 \
            fBl[buf][i] = *(const b8v*)(X + sb + HALF + oB[i]);          \
        }                                                                \
    } while (0)

    LDG(0, 0);
#pragma unroll
    for (int kc = 0; kc < KCHUNK / 32; ++kc) {
        const int cb = kc & 1, nb = cb ^ 1;
        if (kc < KCHUNK / 32 - 1) LDG(nb, kc + 1);
#pragma unroll
        for (int i = 0; i < 4; ++i)
#pragma unroll
            for (int j = 0; j < 4; ++j) {
                acc[i][j] = __builtin_amdgcn_mfma_f32_16x16x32_bf16(fAh[cb][i], fBh[cb][j], acc[i][j], 0, 0, 0);
                acc[i][j] = __builtin_amdgcn_mfma_f32_16x16x32_bf16(fAh[cb][i], fBl[cb][j], acc[i][j], 0, 0, 0);
                acc[i][j] = __builtin_amdgcn_mfma_f32_16x16x32_bf16(fAl[cb][i], fBh[cb][j], acc[i][j], 0, 0, 0);
            }
    }
#undef LDG

    float* pt = part + (((size_t)pairIdx * BATCH + b) * KSPLIT + z) * 4096;
#pragma unroll
    for (int i = 0; i < 4; ++i)
#pragma unroll
        for (int j = 0; j < 4; ++j)
#pragma unroll
            for (int reg = 0; reg < 4; ++reg) {
                int row = i * 16 + q * 4 + reg;
                int col = j * 16 + r;
                pt[row * 64 + col] = acc[i][j][reg];
            }
}

// ---------------------------------------------------------------------------
// reduce partials -> a and z0 (interleaved fragment-major), mirrored via LDS.
// Now also folds the old k_tr: row sums + trace computed from psum/qsum.
// ---------------------------------------------------------------------------
__global__ __launch_bounds__(256) void k_reduce(
    const float* __restrict__ part, const float* __restrict__ psum,
    const float* __restrict__ qsum,
    unsigned short* __restrict__ A, unsigned short* __restrict__ Z,
    float* __restrict__ strbuf) {
    const int b = blockIdx.y;
    int p = blockIdx.x, tm = 0, rem = 4;
    while (p >= rem) { p -= rem; ++tm; --rem; }
    const int tn = tm + p;
    const int t = threadIdx.x;

    // --- row sums + trace (was k_tr) ---
    const float* ps = psum + (size_t)b * KC32 * 256 + t;
    const float* qs = qsum + (size_t)b * KC32 * 256 + t;
    float s0 = 0.f, q0 = 0.f;
#pragma unroll 7
    for (int kc = 0; kc < KC32; ++kc) {
        s0 += ps[(size_t)kc * 256];
        q0 += qs[(size_t)kc * 256];
    }
    __shared__ float ssum[256];
    __shared__ float red[4];
    ssum[t] = s0;
    const float invn = 1.f / (float)HW, invn2 = invn * invn;
    float v = q0 * invn - s0 * s0 * invn2;
    v = wave_sum(v);
    if ((t & 63) == 0) red[t >> 6] = v;
    __syncthreads();
    const float tr = red[0] + red[1] + red[2] + red[3];
    if (blockIdx.x == 0 && t == 0) strbuf[b] = sqrtf(tr);

    // --- partials reduction ---
    const float* pb = part + ((size_t)blockIdx.x * BATCH + b) * KSPLIT * 4096;
    const int row = t >> 2, c0 = (t & 3) * 16;

    float s[16];
#pragma unroll
    for (int u = 0; u < 16; ++u) s[u] = 0.f;
    for (int sp = 0; sp < KSPLIT; ++sp) {
        const float* q4 = pb + sp * 4096 + row * 64 + c0;
#pragma unroll
        for (int u4 = 0; u4 < 4; ++u4) {
            float4 w = *(const float4*)(q4 + u4 * 4);
            s[u4 * 4 + 0] += w.x; s[u4 * 4 + 1] += w.y;
            s[u4 * 4 + 2] += w.z; s[u4 * 4 + 3] += w.w;
        }
    }

    const int gi = tm * 64 + row;
    const float si = ssum[gi];
    const size_t mb = (size_t)b * 8 * SLAB;

    __shared__ unsigned short tAh[64][66], tAl[64][66], tZh[64][66], tZl[64][66];
    unsigned short vAh[16], vAl[16], vZh[16], vZl[16];
#pragma unroll
    for (int u = 0; u < 16; ++u) {
        int gj = tn * 64 + c0 + u;
        float sj = ssum[gj];
        float a = (s[u] * invn - si * sj * invn2) / tr;
        split2(a, vAh[u], vAl[u]);
        float zv = ((gi == gj) ? 1.5f : 0.f) - 0.5f * a;
        split2(zv, vZh[u], vZl[u]);
        tAh[row][c0 + u] = vAh[u]; tAl[row][c0 + u] = vAl[u];
        tZh[row][c0 + u] = vZh[u]; tZl[row][c0 + u] = vZl[u];
    }
#pragma unroll
    for (int u4 = 0; u4 < 4; ++u4) {
        const int col0 = tn * 64 + c0 + u4 * 4;
        const size_t off = mb + (size_t)(col0 >> 5) * SLAB + (size_t)gi * 32 + (col0 & 31);
        *(ushort4*)&A[off] = *(ushort4*)&vAh[u4 * 4];
        *(ushort4*)&A[off + HALF] = *(ushort4*)&vAl[u4 * 4];
        *(ushort4*)&Z[off] = *(ushort4*)&vZh[u4 * 4];
        *(ushort4*)&Z[off + HALF] = *(ushort4*)&vZl[u4 * 4];
    }
    if (tm != tn) {
        __syncthreads();
        const int mr = t >> 2, mc0 = (t & 3) * 16;
        const int gim = tn * 64 + mr;
        unsigned short wAh[16], wAl[16], wZh[16], wZl[16];
#pragma unroll
        for (int u = 0; u < 16; ++u) {
            wAh[u] = tAh[mc0 + u][mr]; wAl[u] = tAl[mc0 + u][mr];
            wZh[u] = tZh[mc0 + u][mr]; wZl[u] = tZl[mc0 + u][mr];
        }
#pragma unroll
        for (int u4 = 0; u4 < 4; ++u4) {
            const int col0 = tm * 64 + mc0 + u4 * 4;
            const size_t off = mb + (size_t)(col0 >> 5) * SLAB + (size_t)gim * 32 + (col0 & 31);
            *(ushort4*)&A[off] = *(ushort4*)&wAh[u4 * 4];
            *(ushort4*)&A[off + HALF] = *(ushort4*)&wAl[u4 * 4];
            *(ushort4*)&Z[off] = *(ushort4*)&wZh[u4 * 4];
            *(ushort4*)&Z[off + HALF] = *(ushort4*)&wZl[u4 * 4];
        }
    }
}

// ---------------------------------------------------------------------------
// NS core: one wave, 32x32 tile, K=256, interleaved fragment-major loads.
// (round-8 structure, best measured)
// ---------------------------------------------------------------------------
__device__ __forceinline__ void wave_gemm32(
    const unsigned short* __restrict__ A, const unsigned short* __restrict__ B,
    int rowA, int rowB, f4v acc[2][2]) {
    const int lane = threadIdx.x & 63;
    const int q = lane >> 4, r = lane & 15;
    int oA[2], oB[2];
#pragma unroll
    for (int i = 0; i < 2; ++i) {
        oA[i] = (rowA + i * 16 + r) * 32 + q * 8;
        oB[i] = (rowB + i * 16 + r) * 32 + q * 8;
    }
    b8v fAh[2][2], fAl[2][2], fBh[2][2], fBl[2][2];
#define LD(buf, kc)                                              \
    do {                                                         \
        const size_t sb = (size_t)(kc) * SLAB;                   \
        for (int i = 0; i < 2; ++i) {                            \
            fAh[buf][i] = *(const b8v*)(A + sb + oA[i]);         \
            fAl[buf][i] = *(const b8v*)(A + sb + HALF + oA[i]);  \
            fBh[buf][i] = *(const b8v*)(B + sb + oB[i]);         \
            fBl[buf][i] = *(const b8v*)(B + sb + HALF + oB[i]);  \
        }                                                        \
    } while (0)

    LD(0, 0);
#pragma unroll
    for (int kc = 0; kc < 8; ++kc) {
        const int cb = kc & 1, nb = cb ^ 1;
        if (kc < 7) LD(nb, kc + 1);
#pragma unroll
        for (int i = 0; i < 2; ++i)
#pragma unroll
            for (int j = 0; j < 2; ++j) {
                acc[i][j] = __builtin_amdgcn_mfma_f32_16x16x32_bf16(fAh[cb][i], fBh[cb][j], acc[i][j], 0, 0, 0);
                acc[i][j] = __builtin_amdgcn_mfma_f32_16x16x32_bf16(fAh[cb][i], fBl[cb][j], acc[i][j], 0, 0, 0);
                acc[i][j] = __builtin_amdgcn_mfma_f32_16x16x32_bf16(fAl[cb][i], fBh[cb][j], acc[i][j], 0, 0, 0);
            }
    }
#undef LD
}

// store one 32x32 result tile into interleaved fragment-major D (direct)
__device__ __forceinline__ void store_tile32(
    unsigned short* __restrict__ D, int tm, int tn, const f4v acc[2][2], bool modeT) {
    const int lane = threadIdx.x & 63, q = lane >> 4, r = lane & 15;
#pragma unroll
    for (int i = 0; i < 2; ++i)
#pragma unroll
        for (int j = 0; j < 2; ++j) {
            const int gj = tn * 32 + j * 16 + r;
            const size_t cbase = (size_t)(gj >> 5) * SLAB + (gj & 31);
#pragma unroll
            for (int reg = 0; reg < 4; ++reg) {
                const int gi = tm * 32 + i * 16 + q * 4 + reg;
                float v = acc[i][j][reg];
                if (modeT) v = ((gi == gj) ? 1.5f : 0.f) - 0.5f * v;
                unsigned short h, l;
                split2(v, h, l);
                D[cbase + (size_t)gi * 32] = h;
                D[cbase + HALF + (size_t)gi * 32] = l;
            }
        }
}

// MODE 0: D = acc ; MODE 1: D = 1.5I - 0.5 acc ; MODE 2: triuvec(acc*sqrt(tr))
// XCD-pinned flat grid: batch b always lands on XCD b%8.
template <int MODE>
__global__ __launch_bounds__(64, 1) void k_t64(
    const unsigned short* __restrict__ A, const unsigned short* __restrict__ B,
    unsigned short* __restrict__ D, float* __restrict__ outF,
    const float* __restrict__ strbuf) {
    const int bid = blockIdx.x;
    const int x8 = bid & 7;
    const int w = bid >> 3;
    int b, tm = 0, tn = 0;
    if (MODE == 2) {
        b = x8 + 8 * (w / 36);
        int p = w % 36, rem = 8;
        while (p >= rem) { p -= rem; ++tm; --rem; }
        tn = tm + p;
    } else {
        b = x8 + 8 * (w >> 6);
        const int tile = w & 63;
        tm = tile >> 3; tn = tile & 7;
    }
    const size_t mo = (size_t)b * 8 * SLAB;
    f4v acc[2][2] = {};
    wave_gemm32(A + mo, B + mo, tm * 32, tn * 32, acc);

    if (MODE == 2) {
        const int lane = threadIdx.x & 63, q = lane >> 4, r = lane & 15;
        const float sc = strbuf[b];
#pragma unroll
        for (int i = 0; i < 2; ++i)
#pragma unroll
            for (int j = 0; j < 2; ++j) {
                const int gj = tn * 32 + j * 16 + r;
#pragma unroll
                for (int reg = 0; reg < 4; ++reg) {
                    const int gi = tm * 32 + i * 16 + q * 4 + reg;
                    if (gj >= gi)
                        outF[(size_t)b * OUTROW + (size_t)(gi * C - (gi * (gi - 1)) / 2) +
                             (gj - gi)] = acc[i][j][reg] * sc;
                }
            }
    } else {
        store_tile32(D + mo, tm, tn, acc, MODE == 1);
    }
}

// fused Ynew = Y@T, Znew = T@Z ; XCD-pinned flat grid (4096 blocks)
__global__ __launch_bounds__(64, 1) void k_yz64(
    const unsigned short* __restrict__ Y, const unsigned short* __restrict__ T,
    const unsigned short* __restrict__ Z,
    unsigned short* __restrict__ Yn, unsigned short* __restrict__ Zn) {
    const int bid = blockIdx.x;
    const int x8 = bid & 7;
    const int w = bid >> 3;                 // 0..511
    const int zz = w >> 8;                  // 0: Y@T, 1: T@Z
    const int ww = w & 255;
    const int b = x8 + 8 * (ww >> 6);
    const int tile = ww & 63;
    const int tm = tile >> 3, tn = tile & 7;

    const unsigned short* Am = zz ? T : Y;
    const unsigned short* Bm = zz ? Z : T;
    unsigned short* Dm = zz ? Zn : Yn;

    const size_t mo = (size_t)b * 8 * SLAB;
    f4v acc[2][2] = {};
    wave_gemm32(Am + mo, Bm + mo, tm * 32, tn * 32, acc);
    store_tile32(Dm + mo, tm, tn, acc, false);
}

// ---------------------------------------------------------------------------
extern "C" void kernel_launch(void* const* d_in, const int* in_sizes, int n_in,
                              void* d_out, int out_size, void* d_ws, size_t ws_size,
                              hipStream_t stream) {
    const float* x = (const float*)d_in[0];
    float* out = (float*)d_out;

    unsigned short* W = (unsigned short*)d_ws;
    const size_t XS = (size_t)BATCH * KC32 * SLAB;   // interleaved X shorts
    const size_t MS = (size_t)BATCH * 8 * SLAB;      // one interleaved matrix set
    unsigned short* X = W;
    float* strbuf = (float*)(X + XS);
    unsigned short* P = (unsigned short*)(strbuf + BATCH);
    unsigned short* PA = P + 0 * MS;
    unsigned short* PB = P + 1 * MS;
    unsigned short* PC = P + 2 * MS;
    unsigned short* PD = P + 3 * MS;
    unsigned short* PE = P + 4 * MS;
    // fp32 gram partials alias PC.. (dead until Y0 is written)
    float* part = (float*)PC;                         // 10*32*7*4096 floats
    // prep sum partials live BEYOND part (k_reduce reads them while writing PA)
    unsigned short* partEnd = PC + (size_t)2 * 10 * BATCH * KSPLIT * 4096;
    float* psum = (float*)partEnd;                    // 32*98*256 floats
    float* qsum = psum + (size_t)BATCH * KC32 * 256;

    k_prep<<<dim3(BATCH * G7 * 4), 256, 0, stream>>>(x, X, psum, qsum);
    k_gram_split<<<dim3(10 * BATCH * KSPLIT), 64, 0, stream>>>(X, part);
    k_reduce<<<dim3(10, BATCH), 256, 0, stream>>>(part, psum, qsum, PA, PB, strbuf);

    dim3 g2048(2048);
    // Y0 = a @ z0 -> PC
    k_t64<0><<<g2048, 64, 0, stream>>>(PA, PB, PC, nullptr, strbuf);
    // it0: T0 = 1.5I - 0.5 Z0@Y0 = PB@PC -> PD ; Y1 = PC@PD -> PA ; Z1 = PD@PB -> PE
    k_t64<1><<<g2048, 64, 0, stream>>>(PB, PC, PD, nullptr, strbuf);
    k_yz64<<<dim3(4096), 64, 0, stream>>>(PC, PD, PB, PA, PE);
    // it1: T1 = PE@PA -> PB ; Y2 = PA@PB -> PC ; Z2 = PB@PE -> PD
    k_t64<1><<<g2048, 64, 0, stream>>>(PE, PA, PB, nullptr, strbuf);
    k_yz64<<<dim3(4096), 64, 0, stream>>>(PA, PB, PE, PC, PD);
    // it2: T2 = PD@PC -> PA ; Y3 = PC@PA -> PB ; Z3 = PA@PD -> PE
    k_t64<1><<<g2048, 64, 0, stream>>>(PD, PC, PA, nullptr, strbuf);
    k_yz64<<<dim3(4096), 64, 0, stream>>>(PC, PA, PD, PB, PE);
    // it3: T3 = PE@PB -> PC ; out = triuvec((PB@PC) * sqrt(tr))
    k_t64<1><<<g2048, 64, 0, stream>>>(PE, PB, PC, nullptr, strbuf);
    k_t64<2><<<dim3(1152), 64, 0, stream>>>(PB, PC, nullptr, out, strbuf);
}

// Round 11
// 339.771 us; speedup vs baseline: 7.3467x; 1.0658x over previous
//
#include <hip/hip_runtime.h>
#include <hip/hip_bf16.h>
#include <math.h>

#define BATCH 32
#define C 256
#define HW 3136
#define OUTROW 32896
#define KSPLIT 7
#define KCHUNK 448   // HW / KSPLIT
#define KC32 98      // HW / 32
#define G7 14        // 7-kc groups per batch
#define SLAB 16384   // shorts per kc slab (hi 8192 + lo 8192 interleaved)
#define HALF 8192
#define LKС 0

// Interleaved fragment-major layouts (shorts):
//   X slab s = b*98 + kc :  X[s*SLAB + row*32 + (k&31)]        (hi)
//                           X[s*SLAB + HALF + row*32 + (k&31)] (lo)
//   M slab s = b*8 + kc  :  same, 256x256 matrices, 8 slabs each.

typedef __bf16 b8v __attribute__((ext_vector_type(8)));
typedef float  f4v __attribute__((ext_vector_type(4)));
typedef unsigned short u16x8 __attribute__((ext_vector_type(8)));

__device__ __forceinline__ unsigned short f2bf(float f) {
    union { float f; unsigned u; } v; v.f = f;
    unsigned r = v.u + 0x7FFFu + ((v.u >> 16) & 1u);
    return (unsigned short)(r >> 16);
}
__device__ __forceinline__ float bf2f(unsigned short h) {
    union { unsigned u; float f; } v; v.u = ((unsigned)h) << 16; return v.f;
}
__device__ __forceinline__ void split2(float x, unsigned short& h, unsigned short& l) {
    h = f2bf(x);
    l = f2bf(x - bf2f(h));
}

__device__ __forceinline__ float wave_sum(float v) {
    for (int o = 32; o; o >>= 1) v += __shfl_down(v, o, 64);
    return v;
}

// ---------------------------------------------------------------------------
// prep: x -> hi/lo bf16 split, interleaved fragment-major X layout.
// Block (b, 7-kc group, 64-row quad). Phase 1: lane owns one kc, reads its
// contiguous 128 B per row (7 lanes = 896-B windows), splits, stages to LDS.
// Phase 2: cooperative write-out in slab order — 4 lanes x 16 B per row,
// 16 rows/wave = 1 KB contiguous per slab (full-line writes, no RMW).
// ---------------------------------------------------------------------------
#define KCSTRIDE 2308   // shorts; 1154 words, mod 32 = 2 -> kc spreads banks
__global__ __launch_bounds__(256, 2) void k_prep(const float* __restrict__ x,
                                                 unsigned short* __restrict__ X,
                                                 float* __restrict__ psum,
                                                 float* __restrict__ qsum) {
    const int bid = blockIdx.x;
    const int quad = bid & 3;
    const int bg = bid >> 2;          // b*G7 + g
    const int b = bg / G7;
    const int g = bg - b * G7;
    const int t = threadIdx.x;

    __shared__ unsigned short lh[7 * KCSTRIDE];   // row stride 36 shorts
    __shared__ unsigned short ll[7 * KCSTRIDE];
    __shared__ float ssq[2][7][64];

    const bool act = t < 224;         // 7 kc x 32 row-slots
    const int j = t % 7;
    const int r32 = t / 7;            // 0..31
    const int kc = g * 7 + j;

    if (act) {
        const float* xb = x + (size_t)b * C * HW + (size_t)(quad * 64) * HW + (size_t)kc * 32;
#pragma unroll
        for (int p = 0; p < 2; ++p) {
            const int row = p * 32 + r32;                 // 0..63 local
            const float* src = xb + (size_t)row * HW;
            float4 v[8];
#pragma unroll
            for (int u = 0; u < 8; ++u) v[u] = *(const float4*)(src + u * 4);
            unsigned short* lhr = lh + j * KCSTRIDE + row * 36;
            unsigned short* llr = ll + j * KCSTRIDE + row * 36;
            float s = 0.f, q = 0.f;
#pragma unroll
            for (int u = 0; u < 8; ++u) {
                ushort4 h4, l4;
                split2(v[u].x, h4.x, l4.x); split2(v[u].y, h4.y, l4.y);
                split2(v[u].z, h4.z, l4.z); split2(v[u].w, h4.w, l4.w);
                *(ushort4*)(lhr + u * 4) = h4;
                *(ushort4*)(llr + u * 4) = l4;
                s += v[u].x + v[u].y + v[u].z + v[u].w;
                q = fmaf(v[u].x, v[u].x, q); q = fmaf(v[u].y, v[u].y, q);
                q = fmaf(v[u].z, v[u].z, q); q = fmaf(v[u].w, v[u].w, q);
            }
            ssq[0][j][row] = s;
            ssq[1][j][row] = q;
        }
    }
    __syncthreads();

    // phase 2: slab-order write-out (1 KB contiguous per wave per slab)
    const int wrow = t >> 2;          // 0..63
    const int wo = (t & 3) * 8;       // 0,8,16,24
#pragma unroll
    for (int kcw = 0; kcw < 7; ++kcw) {
        unsigned short* dst = X + (size_t)(b * KC32 + g * 7 + kcw) * SLAB +
                              (size_t)(quad * 64 + wrow) * 32 + wo;
        const unsigned short* sh = lh + kcw * KCSTRIDE + wrow * 36 + wo;
        const unsigned short* sl = ll + kcw * KCSTRIDE + wrow * 36 + wo;
        union { ushort4 u4[2]; u16x8 u8; } hv, lv;
        hv.u4[0] = *(const ushort4*)(sh);
        hv.u4[1] = *(const ushort4*)(sh + 4);
        lv.u4[0] = *(const ushort4*)(sl);
        lv.u4[1] = *(const ushort4*)(sl + 4);
        *(u16x8*)dst = hv.u8;
        *(u16x8*)(dst + HALF) = lv.u8;
    }

    // s/q: reduce 7 kc per row, write per-(b,g,row) partial
    if (t < 64) {
        float s = 0.f, q = 0.f;
#pragma unroll
        for (int k7 = 0; k7 < 7; ++k7) { s += ssq[0][k7][t]; q += ssq[1][k7][t]; }
        const size_t o = ((size_t)b * G7 + g) * 256 + quad * 64 + t;
        psum[o] = s;
        qsum[o] = q;
    }
}

// ---------------------------------------------------------------------------
// gram split-K: 1-wave blocks, 64x64 tile, fragment-major coalesced loads,
// register dbuf, XCD-pinned. Grid 2240 x 64.
// ---------------------------------------------------------------------------
__global__ __launch_bounds__(64, 1) void k_gram_split(
    const unsigned short* __restrict__ X, float* __restrict__ part) {
    const int bid = blockIdx.x;
    const int x8 = bid & 7;
    const int t8 = bid >> 3;
    const int pairIdx = t8 % 10;
    const int g = (t8 / 10) * 8 + x8;   // 0..223, pinned to XCD x8
    const int b = g & 31;
    const int z = g >> 5;               // 0..6

    int p = pairIdx, tm = 0, rem = 4;
    while (p >= rem) { p -= rem; ++tm; --rem; }
    const int tn = tm + p;

    const int lane = threadIdx.x & 63;
    const int q = lane >> 4, r = lane & 15;
    const int kc0 = z * (KCHUNK / 32);
    const size_t matb = (size_t)b * KC32 * SLAB;

    int oA[4], oB[4];
#pragma unroll
    for (int i = 0; i < 4; ++i) {
        oA[i] = (tm * 64 + i * 16 + r) * 32 + q * 8;
        oB[i] = (tn * 64 + i * 16 + r) * 32 + q * 8;
    }

    f4v acc[4][4] = {};
    b8v fAh[2][4], fAl[2][4], fBh[2][4], fBl[2][4];
#define LDG(buf, kc)                                                     \
    do {                                                                 \
        const size_t sb = matb + (size_t)(kc0 + (kc)) * SLAB;            \
        for (int i = 0; i < 4; ++i) {                                    \
            fAh[buf][i] = *(const b8v*)(X + sb + oA[i]);                 \
            fAl[buf][i] = *(const b8v*)(X + sb + HALF + oA[i]);          \
            fBh[buf][i] = *(const b8v*)(X + sb + oB[i]);                 \
            fBl[buf][i] = *(const b8v*)(X + sb + HALF + oB[i]);          \
        }                                                                \
    } while (0)

    LDG(0, 0);
#pragma unroll
    for (int kc = 0; kc < KCHUNK / 32; ++kc) {
        const int cb = kc & 1, nb = cb ^ 1;
        if (kc < KCHUNK / 32 - 1) LDG(nb, kc + 1);
#pragma unroll
        for (int i = 0; i < 4; ++i)
#pragma unroll
            for (int j = 0; j < 4; ++j) {
                acc[i][j] = __builtin_amdgcn_mfma_f32_16x16x32_bf16(fAh[cb][i], fBh[cb][j], acc[i][j], 0, 0, 0);
                acc[i][j] = __builtin_amdgcn_mfma_f32_16x16x32_bf16(fAh[cb][i], fBl[cb][j], acc[i][j], 0, 0, 0);
                acc[i][j] = __builtin_amdgcn_mfma_f32_16x16x32_bf16(fAl[cb][i], fBh[cb][j], acc[i][j], 0, 0, 0);
            }
    }
#undef LDG

    float* pt = part + (((size_t)pairIdx * BATCH + b) * KSPLIT + z) * 4096;
#pragma unroll
    for (int i = 0; i < 4; ++i)
#pragma unroll
        for (int j = 0; j < 4; ++j)
#pragma unroll
            for (int reg = 0; reg < 4; ++reg) {
                int row = i * 16 + q * 4 + reg;
                int col = j * 16 + r;
                pt[row * 64 + col] = acc[i][j][reg];
            }
}

// ---------------------------------------------------------------------------
// reduce partials -> a and z0 (interleaved fragment-major), mirrored via LDS.
// Folds the old k_tr: row sums + trace computed from psum/qsum (14 groups).
// ---------------------------------------------------------------------------
__global__ __launch_bounds__(256) void k_reduce(
    const float* __restrict__ part, const float* __restrict__ psum,
    const float* __restrict__ qsum,
    unsigned short* __restrict__ A, unsigned short* __restrict__ Z,
    float* __restrict__ strbuf) {
    const int b = blockIdx.y;
    int p = blockIdx.x, tm = 0, rem = 4;
    while (p >= rem) { p -= rem; ++tm; --rem; }
    const int tn = tm + p;
    const int t = threadIdx.x;

    // --- row sums + trace (was k_tr) ---
    const float* ps = psum + (size_t)b * G7 * 256 + t;
    const float* qs = qsum + (size_t)b * G7 * 256 + t;
    float s0 = 0.f, q0 = 0.f;
#pragma unroll
    for (int g = 0; g < G7; ++g) {
        s0 += ps[(size_t)g * 256];
        q0 += qs[(size_t)g * 256];
    }
    __shared__ float ssum[256];
    __shared__ float red[4];
    ssum[t] = s0;
    const float invn = 1.f / (float)HW, invn2 = invn * invn;
    float v = q0 * invn - s0 * s0 * invn2;
    v = wave_sum(v);
    if ((t & 63) == 0) red[t >> 6] = v;
    __syncthreads();
    const float tr = red[0] + red[1] + red[2] + red[3];
    if (blockIdx.x == 0 && t == 0) strbuf[b] = sqrtf(tr);

    // --- partials reduction ---
    const float* pb = part + ((size_t)blockIdx.x * BATCH + b) * KSPLIT * 4096;
    const int row = t >> 2, c0 = (t & 3) * 16;

    float s[16];
#pragma unroll
    for (int u = 0; u < 16; ++u) s[u] = 0.f;
    for (int sp = 0; sp < KSPLIT; ++sp) {
        const float* q4 = pb + sp * 4096 + row * 64 + c0;
#pragma unroll
        for (int u4 = 0; u4 < 4; ++u4) {
            float4 w = *(const float4*)(q4 + u4 * 4);
            s[u4 * 4 + 0] += w.x; s[u4 * 4 + 1] += w.y;
            s[u4 * 4 + 2] += w.z; s[u4 * 4 + 3] += w.w;
        }
    }

    const int gi = tm * 64 + row;
    const float si = ssum[gi];
    const size_t mb = (size_t)b * 8 * SLAB;

    __shared__ unsigned short tAh[64][66], tAl[64][66], tZh[64][66], tZl[64][66];
    unsigned short vAh[16], vAl[16], vZh[16], vZl[16];
#pragma unroll
    for (int u = 0; u < 16; ++u) {
        int gj = tn * 64 + c0 + u;
        float sj = ssum[gj];
        float a = (s[u] * invn - si * sj * invn2) / tr;
        split2(a, vAh[u], vAl[u]);
        float zv = ((gi == gj) ? 1.5f : 0.f) - 0.5f * a;
        split2(zv, vZh[u], vZl[u]);
        tAh[row][c0 + u] = vAh[u]; tAl[row][c0 + u] = vAl[u];
        tZh[row][c0 + u] = vZh[u]; tZl[row][c0 + u] = vZl[u];
    }
#pragma unroll
    for (int u4 = 0; u4 < 4; ++u4) {
        const int col0 = tn * 64 + c0 + u4 * 4;
        const size_t off = mb + (size_t)(col0 >> 5) * SLAB + (size_t)gi * 32 + (col0 & 31);
        *(ushort4*)&A[off] = *(ushort4*)&vAh[u4 * 4];
        *(ushort4*)&A[off + HALF] = *(ushort4*)&vAl[u4 * 4];
        *(ushort4*)&Z[off] = *(ushort4*)&vZh[u4 * 4];
        *(ushort4*)&Z[off + HALF] = *(ushort4*)&vZl[u4 * 4];
    }
    if (tm != tn) {
        __syncthreads();
        const int mr = t >> 2, mc0 = (t & 3) * 16;
        const int gim = tn * 64 + mr;
        unsigned short wAh[16], wAl[16], wZh[16], wZl[16];
#pragma unroll
        for (int u = 0; u < 16; ++u) {
            wAh[u] = tAh[mc0 + u][mr]; wAl[u] = tAl[mc0 + u][mr];
            wZh[u] = tZh[mc0 + u][mr]; wZl[u] = tZl[mc0 + u][mr];
        }
#pragma unroll
        for (int u4 = 0; u4 < 4; ++u4) {
            const int col0 = tm * 64 + mc0 + u4 * 4;
            const size_t off = mb + (size_t)(col0 >> 5) * SLAB + (size_t)gim * 32 + (col0 & 31);
            *(ushort4*)&A[off] = *(ushort4*)&wAh[u4 * 4];
            *(ushort4*)&A[off + HALF] = *(ushort4*)&wAl[u4 * 4];
            *(ushort4*)&Z[off] = *(ushort4*)&wZh[u4 * 4];
            *(ushort4*)&Z[off + HALF] = *(ushort4*)&wZl[u4 * 4];
        }
    }
}

// ---------------------------------------------------------------------------
// NS core: one wave, 32x32 tile, K=256, interleaved fragment-major loads.
// (round-8 structure, best measured)
// ---------------------------------------------------------------------------
__device__ __forceinline__ void wave_gemm32(
    const unsigned short* __restrict__ A, const unsigned short* __restrict__ B,
    int rowA, int rowB, f4v acc[2][2]) {
    const int lane = threadIdx.x & 63;
    const int q = lane >> 4, r = lane & 15;
    int oA[2], oB[2];
#pragma unroll
    for (int i = 0; i < 2; ++i) {
        oA[i] = (rowA + i * 16 + r) * 32 + q * 8;
        oB[i] = (rowB + i * 16 + r) * 32 + q * 8;
    }
    b8v fAh[2][2], fAl[2][2], fBh[2][2], fBl[2][2];
#define LD(buf, kc)                                              \
    do {                                                         \
        const size_t sb = (size_t)(kc) * SLAB;                   \
        for (int i = 0; i < 2; ++i) {                            \
            fAh[buf][i] = *(const b8v*)(A + sb + oA[i]);         \
            fAl[buf][i] = *(const b8v*)(A + sb + HALF + oA[i]);  \
            fBh[buf][i] = *(const b8v*)(B + sb + oB[i]);         \
            fBl[buf][i] = *(const b8v*)(B + sb + HALF + oB[i]);  \
        }                                                        \
    } while (0)

    LD(0, 0);
#pragma unroll
    for (int kc = 0; kc < 8; ++kc) {
        const int cb = kc & 1, nb = cb ^ 1;
        if (kc < 7) LD(nb, kc + 1);
#pragma unroll
        for (int i = 0; i < 2; ++i)
#pragma unroll
            for (int j = 0; j < 2; ++j) {
                acc[i][j] = __builtin_amdgcn_mfma_f32_16x16x32_bf16(fAh[cb][i], fBh[cb][j], acc[i][j], 0, 0, 0);
                acc[i][j] = __builtin_amdgcn_mfma_f32_16x16x32_bf16(fAh[cb][i], fBl[cb][j], acc[i][j], 0, 0, 0);
                acc[i][j] = __builtin_amdgcn_mfma_f32_16x16x32_bf16(fAl[cb][i], fBh[cb][j], acc[i][j], 0, 0, 0);
            }
    }
#undef LD
}

// store one 32x32 result tile into interleaved fragment-major D (direct)
__device__ __forceinline__ void store_tile32(
    unsigned short* __restrict__ D, int tm, int tn, const f4v acc[2][2], bool modeT) {
    const int lane = threadIdx.x & 63, q = lane >> 4, r = lane & 15;
#pragma unroll
    for (int i = 0; i < 2; ++i)
#pragma unroll
        for (int j = 0; j < 2; ++j) {
            const int gj = tn * 32 + j * 16 + r;
            const size_t cbase = (size_t)(gj >> 5) * SLAB + (gj & 31);
#pragma unroll
            for (int reg = 0; reg < 4; ++reg) {
                const int gi = tm * 32 + i * 16 + q * 4 + reg;
                float v = acc[i][j][reg];
                if (modeT) v = ((gi == gj) ? 1.5f : 0.f) - 0.5f * v;
                unsigned short h, l;
                split2(v, h, l);
                D[cbase + (size_t)gi * 32] = h;
                D[cbase + HALF + (size_t)gi * 32] = l;
            }
        }
}

// MODE 0: D = acc ; MODE 1: D = 1.5I - 0.5 acc ; MODE 2: triuvec(acc*sqrt(tr))
// XCD-pinned flat grid: batch b always lands on XCD b%8.
template <int MODE>
__global__ __launch_bounds__(64, 1) void k_t64(
    const unsigned short* __restrict__ A, const unsigned short* __restrict__ B,
    unsigned short* __restrict__ D, float* __restrict__ outF,
    const float* __restrict__ strbuf) {
    const int bid = blockIdx.x;
    const int x8 = bid & 7;
    const int w = bid >> 3;
    int b, tm = 0, tn = 0;
    if (MODE == 2) {
        b = x8 + 8 * (w / 36);
        int p = w % 36, rem = 8;
        while (p >= rem) { p -= rem; ++tm; --rem; }
        tn = tm + p;
    } else {
        b = x8 + 8 * (w >> 6);
        const int tile = w & 63;
        tm = tile >> 3; tn = tile & 7;
    }
    const size_t mo = (size_t)b * 8 * SLAB;
    f4v acc[2][2] = {};
    wave_gemm32(A + mo, B + mo, tm * 32, tn * 32, acc);

    if (MODE == 2) {
        const int lane = threadIdx.x & 63, q = lane >> 4, r = lane & 15;
        const float sc = strbuf[b];
#pragma unroll
        for (int i = 0; i < 2; ++i)
#pragma unroll
            for (int j = 0; j < 2; ++j) {
                const int gj = tn * 32 + j * 16 + r;
#pragma unroll
                for (int reg = 0; reg < 4; ++reg) {
                    const int gi = tm * 32 + i * 16 + q * 4 + reg;
                    if (gj >= gi)
                        outF[(size_t)b * OUTROW + (size_t)(gi * C - (gi * (gi - 1)) / 2) +
                             (gj - gi)] = acc[i][j][reg] * sc;
                }
            }
    } else {
        store_tile32(D + mo, tm, tn, acc, MODE == 1);
    }
}

// fused Ynew = Y@T, Znew = T@Z ; XCD-pinned flat grid (4096 blocks)
__global__ __launch_bounds__(64, 1) void k_yz64(
    const unsigned short* __restrict__ Y, const unsigned short* __restrict__ T,
    const unsigned short* __restrict__ Z,
    unsigned short* __restrict__ Yn, unsigned short* __restrict__ Zn) {
    const int bid = blockIdx.x;
    const int x8 = bid & 7;
    const int w = bid >> 3;                 // 0..511
    const int zz = w >> 8;                  // 0: Y@T, 1: T@Z
    const int ww = w & 255;
    const int b = x8 + 8 * (ww >> 6);
    const int tile = ww & 63;
    const int tm = tile >> 3, tn = tile & 7;

    const unsigned short* Am = zz ? T : Y;
    const unsigned short* Bm = zz ? Z : T;
    unsigned short* Dm = zz ? Zn : Yn;

    const size_t mo = (size_t)b * 8 * SLAB;
    f4v acc[2][2] = {};
    wave_gemm32(Am + mo, Bm + mo, tm * 32, tn * 32, acc);
    store_tile32(Dm + mo, tm, tn, acc, false);
}

// ---------------------------------------------------------------------------
extern "C" void kernel_launch(void* const* d_in, const int* in_sizes, int n_in,
                              void* d_out, int out_size, void* d_ws, size_t ws_size,
                              hipStream_t stream) {
    const float* x = (const float*)d_in[0];
    float* out = (float*)d_out;

    unsigned short* W = (unsigned short*)d_ws;
    const size_t XS = (size_t)BATCH * KC32 * SLAB;   // interleaved X shorts
    const size_t MS = (size_t)BATCH * 8 * SLAB;      // one interleaved matrix set
    unsigned short* X = W;
    float* strbuf = (float*)(X + XS);
    unsigned short* P = (unsigned short*)(strbuf + BATCH);
    unsigned short* PA = P + 0 * MS;
    unsigned short* PB = P + 1 * MS;
    unsigned short* PC = P + 2 * MS;
    unsigned short* PD = P + 3 * MS;
    unsigned short* PE = P + 4 * MS;
    // fp32 gram partials alias PC.. (dead until Y0 is written)
    float* part = (float*)PC;                         // 10*32*7*4096 floats
    // prep sum partials live BEYOND part (k_reduce reads them while writing PA)
    unsigned short* partEnd = PC + (size_t)2 * 10 * BATCH * KSPLIT * 4096;
    float* psum = (float*)partEnd;                    // 32*14*256 floats
    float* qsum = psum + (size_t)BATCH * G7 * 256;

    k_prep<<<dim3(BATCH * G7 * 4), 256, 0, stream>>>(x, X, psum, qsum);
    k_gram_split<<<dim3(10 * BATCH * KSPLIT), 64, 0, stream>>>(X, part);
    k_reduce<<<dim3(10, BATCH), 256, 0, stream>>>(part, psum, qsum, PA, PB, strbuf);

    dim3 g2048(2048);
    // Y0 = a @ z0 -> PC
    k_t64<0><<<g2048, 64, 0, stream>>>(PA, PB, PC, nullptr, strbuf);
    // it0: T0 = 1.5I - 0.5 Z0@Y0 = PB@PC -> PD ; Y1 = PC@PD -> PA ; Z1 = PD@PB -> PE
    k_t64<1><<<g2048, 64, 0, stream>>>(PB, PC, PD, nullptr, strbuf);
    k_yz64<<<dim3(4096), 64, 0, stream>>>(PC, PD, PB, PA, PE);
    // it1: T1 = PE@PA -> PB ; Y2 = PA@PB -> PC ; Z2 = PB@PE -> PD
    k_t64<1><<<g2048, 64, 0, stream>>>(PE, PA, PB, nullptr, strbuf);
    k_yz64<<<dim3(4096), 64, 0, stream>>>(PA, PB, PE, PC, PD);
    // it2: T2 = PD@PC -> PA ; Y3 = PC@PA -> PB ; Z3 = PA@PD -> PE
    k_t64<1><<<g2048, 64, 0, stream>>>(PD, PC, PA, nullptr, strbuf);
    k_yz64<<<dim3(4096), 64, 0, stream>>>(PC, PA, PD, PB, PE);
    // it3: T3 = PE@PB -> PC ; out = triuvec((PB@PC) * sqrt(tr))
    k_t64<1><<<g2048, 64, 0, stream>>>(PE, PB, PC, nullptr, strbuf);
    k_t64<2><<<dim3(1152), 64, 0, stream>>>(PB, PC, nullptr, out, strbuf);
}